// Round 8
// baseline (163.520 us; speedup 1.0000x reference)
//
#include <hip/hip_runtime.h>
#include <hip/hip_bf16.h>
#include <stdint.h>

#define DI __device__ __forceinline__

typedef float f32x4 __attribute__((ext_vector_type(4)));
typedef short bf16x8 __attribute__((ext_vector_type(8)));

constexpr int BB = 8192, TT = 128, DD = 16, HH = 32;
constexpr float kEPS = 1e-5f;
constexpr float kLOG2E = 1.44269504088896340736f;

// ---------------- helpers ----------------
DI float rcpf_(float x) { return __builtin_amdgcn_rcpf(x); }
DI float exp2f_(float x) { return __builtin_amdgcn_exp2f(x); }
DI float sigm(float x) { return rcpf_(1.0f + exp2f_(-kLOG2E * x)); }

DI uint32_t cvtpk(float lo, float hi) {
  uint32_t r;
  asm("v_cvt_pk_bf16_f32 %0, %1, %2" : "=v"(r) : "v"(lo), "v"(hi));
  return r;
}

DI f32x4 mfma_(bf16x8 a, bf16x8 b, f32x4 c) {
  return __builtin_amdgcn_mfma_f32_16x16x32_bf16(a, b, c, 0, 0, 0);
}

// Pin a value into VGPRs as an opaque register: the compiler can no longer
// rematerialize it via a reload, so it stays register-resident across the
// loop (defeats the per-step L1 reload chain caused by "memory" clobbers).
#define PIN(x) asm volatile("" : "+v"(x))

union U4 { uint4 q; bf16x8 v; };

// ---------------- weight prep (per net) ----------------
// W tiles are the MFMA *A* operand, state is *B*.
// A-frag: lane l holds A[row=l&15][k=8*(l>>4)+j], natural k order.
// ws per-net block (32 KiB stride):
//   u16[27*512]: 27 tiles (Wih0 r0 r1 z0 z1 n0 n1 | Whh0 ... | Wih1 ... |
//                Whh1 ... | emb e0 e1 | out), each tile = 64 lanes x 8 bf16.
//   f32[304] at byte 27648: 19 bias tiles x 16
//   (L0: r0 r1 z0 z1 i0 i1 h0 h1 | L1: same | e0 e1 | out)
__global__ void prep_net(const float* Wih0, const float* Whh0,
                         const float* bih0, const float* bhh0,
                         const float* Wih1, const float* Whh1,
                         const float* bih1, const float* bhh1,
                         const float* embW, const float* embB,
                         const float* bng, const float* bnb,
                         const float* bnm, const float* bnv,
                         const float* outW, const float* outB,
                         int outDim, uint8_t* wsbase) {
  int tid = threadIdx.x;
  uint16_t* W = (uint16_t*)wsbase;
  float* bias = (float*)(wsbase + 27648);
  auto cvt = [](float f) -> uint16_t {
    union { float f; uint32_t u; } v; v.f = f;
    uint32_t u = v.u;
    return (uint16_t)((u + 0x7FFF + ((u >> 16) & 1)) >> 16);  // RNE
  };
  for (int idx = tid; idx < 27 * 64; idx += 256) {
    int tile = idx >> 6, l = idx & 63, cc = l & 15, gg = l >> 4;
    uint16_t* dst = W + (size_t)idx * 8;
    if (tile < 24) {
      const float* mats[4] = {Wih0, Whh0, Wih1, Whh1};
      const float* src = mats[tile / 6];
      int sub = tile % 6;                   // r0 r1 z0 z1 n0 n1
      int row = sub * 16 + cc;              // rows: r 0-31, z 32-63, n 64-95
      float sc = (sub < 4) ? -kLOG2E : 2.0f * kLOG2E;
#pragma unroll
      for (int j = 0; j < 8; ++j) dst[j] = cvt(src[row * 32 + 8 * gg + j] * sc);
    } else if (tile < 26) {
      int row = (tile - 24) * 16 + cc;
      float a = bng[row] * rsqrtf(bnv[row] + kEPS);
#pragma unroll
      for (int j = 0; j < 8; ++j) dst[j] = cvt(embW[row * 32 + 8 * gg + j] * a);
    } else {
      int rrow = (cc < outDim) ? cc : 0;
      float sc = (cc < outDim) ? 1.0f : 0.0f;
#pragma unroll
      for (int j = 0; j < 8; ++j) dst[j] = cvt(outW[rrow * 32 + 8 * gg + j] * sc);
    }
  }
  for (int idx = tid; idx < 304; idx += 256) {
    int tile = idx >> 4, n = idx & 15;
    float v;
    if (tile < 8) {
      if (tile < 4)      v = (bih0[tile * 16 + n] + bhh0[tile * 16 + n]) * (-kLOG2E);
      else if (tile < 6) v = bih0[64 + (tile - 4) * 16 + n] * (2.0f * kLOG2E);
      else               v = bhh0[64 + (tile - 6) * 16 + n] * (2.0f * kLOG2E);
    } else if (tile < 16) {
      int tt = tile - 8;
      if (tt < 4)        v = (bih1[tt * 16 + n] + bhh1[tt * 16 + n]) * (-kLOG2E);
      else if (tt < 6)   v = bih1[64 + (tt - 4) * 16 + n] * (2.0f * kLOG2E);
      else               v = bhh1[64 + (tt - 6) * 16 + n] * (2.0f * kLOG2E);
    } else if (tile < 18) {
      int nn = (tile - 16) * 16 + n;
      float a = bng[nn] * rsqrtf(bnv[nn] + kEPS);
      v = a * (embB[nn] - bnm[nn]) + bnb[nn];
    } else {
      v = (n < outDim) ? outB[n] : 0.0f;
    }
    bias[idx] = v;
  }
}

// ------- fused RNN + heads: async producer/consumer, weights PINNED -------
// Block = 128 threads = 2 waves, one batch group (16 rows) of one net.
// Wave A: layer-0 recurrence -> h0 ring (depth 8) + prod flag.
// Wave B: layer-1 + head, consumes ring at its own pace + cons flag.
__global__ __launch_bounds__(128, 2) void rnn_fused(
    const float* __restrict__ S, const float* __restrict__ gS,
    const float* __restrict__ hp0, const float* __restrict__ hd0,
    const uint8_t* __restrict__ ws, float* __restrict__ out) {
  const int tid = threadIdx.x, lane = tid & 63, wid = tid >> 6;
  const int net = blockIdx.x & 1;                 // 0 = price, 1 = delta
  const int b0 = (blockIdx.x >> 1) * 16;
  const int c = lane & 15, g = lane >> 4;

  const uint16_t* W = (const uint16_t*)(ws + net * 32768);
  const float* bias = (const float*)(ws + net * 32768 + 27648);
  const float* hsrc = net ? hd0 : hp0;

  __shared__ uint4 ring0[8][64];                  // h0B frags, depth 8
  __shared__ volatile int flags[2];               // 0 = prod, 1 = cons
  if (tid < 2) flags[tid] = 0;
  __syncthreads();                                // the only block barrier

  auto waitGE = [&](int idx, int target) {
    if (flags[idx] >= target) return;
    do { __builtin_amdgcn_s_sleep(1); } while (flags[idx] < target);
  };

  // regroup: gate-layout f32 v[8] -> B-frag, 8 bpermute + 4 sel.
  const int addr0 = ((lane & 15) | ((lane & 16) << 1)) << 2;
  const int addr1 = addr0 + 64;
  const bool lo32 = lane < 32;
  auto regroup = [&](const float (&v)[8]) -> bf16x8 {
    int P0 = (int)cvtpk(v[0], v[1]), P1 = (int)cvtpk(v[2], v[3]);
    int Q0 = (int)cvtpk(v[4], v[5]), Q1 = (int)cvtpk(v[6], v[7]);
    union { uint32_t u[4]; bf16x8 r; } t;
    int a, b;
    a = __builtin_amdgcn_ds_bpermute(addr0, P0);
    b = __builtin_amdgcn_ds_bpermute(addr0, Q0);
    t.u[0] = lo32 ? a : b;
    a = __builtin_amdgcn_ds_bpermute(addr0, P1);
    b = __builtin_amdgcn_ds_bpermute(addr0, Q1);
    t.u[1] = lo32 ? a : b;
    a = __builtin_amdgcn_ds_bpermute(addr1, P0);
    b = __builtin_amdgcn_ds_bpermute(addr1, Q0);
    t.u[2] = lo32 ? a : b;
    a = __builtin_amdgcn_ds_bpermute(addr1, P1);
    b = __builtin_amdgcn_ds_bpermute(addr1, Q1);
    t.u[3] = lo32 ? a : b;
    return t.r;
  };

  // GRU step, fused-rcp algebra:
  //   h' = [(h-Ez) + En*(h+Ez)] * rcp[(1+En)(1+Ez)]   (exact)
  auto gruStep = [&](const bf16x8 (&Wi)[6], const bf16x8 (&Wh)[6],
                     const f32x4 (&Bb)[8], bf16x8 xf, bf16x8 hf,
                     float (&hC)[8]) {
    f32x4 r0 = mfma_(Wi[0], xf, Bb[0]); r0 = mfma_(Wh[0], hf, r0);
    f32x4 r1 = mfma_(Wi[1], xf, Bb[1]); r1 = mfma_(Wh[1], hf, r1);
    f32x4 z0 = mfma_(Wi[2], xf, Bb[2]); z0 = mfma_(Wh[2], hf, z0);
    f32x4 z1 = mfma_(Wi[3], xf, Bb[3]); z1 = mfma_(Wh[3], hf, z1);
    f32x4 ni0 = mfma_(Wi[4], xf, Bb[4]);
    f32x4 ni1 = mfma_(Wi[5], xf, Bb[5]);
    f32x4 nh0 = mfma_(Wh[4], hf, Bb[6]);
    f32x4 nh1 = mfma_(Wh[5], hf, Bb[7]);
#pragma unroll
    for (int r = 0; r < 4; ++r) {
      float rg0 = rcpf_(1.0f + exp2f_(r0[r]));
      float rg1 = rcpf_(1.0f + exp2f_(r1[r]));
      float w0 = ni0[r] + rg0 * nh0[r];
      float w1 = ni1[r] + rg1 * nh1[r];
      float En0 = exp2f_(w0), En1 = exp2f_(w1);
      float Ez0 = exp2f_(z0[r]), Ez1 = exp2f_(z1[r]);
      float hv0 = hC[r], hv1 = hC[4 + r];
      float num0 = (hv0 - Ez0) + En0 * (hv0 + Ez0);
      float num1 = (hv1 - Ez1) + En1 * (hv1 + Ez1);
      float den0 = (1.0f + En0) * (1.0f + Ez0);
      float den1 = (1.0f + En1) * (1.0f + Ez1);
      hC[r]     = num0 * rcpf_(den0);
      hC[4 + r] = num1 * rcpf_(den1);
    }
  };

  auto mkB = [&](const float* row) -> bf16x8 {
    f32x4 a = *(const f32x4*)(row);
    f32x4 b = *(const f32x4*)(row + 4);
    union { uint32_t u[4]; bf16x8 v; } t;
    t.u[0] = cvtpk(a[0], a[1]); t.u[1] = cvtpk(a[2], a[3]);
    t.u[2] = cvtpk(b[0], b[1]); t.u[3] = cvtpk(b[2], b[3]);
    return t.v;
  };

  if (wid == 0) {
    // ================= wave A: layer-0 recurrence (producer) =============
    bf16x8 Wi[6], Wh[6];
#pragma unroll
    for (int t = 0; t < 6; ++t) {
      Wi[t] = *(const bf16x8*)(W + ((0 + t) * 64 + lane) * 8);
      Wh[t] = *(const bf16x8*)(W + ((6 + t) * 64 + lane) * 8);
      PIN(Wi[t]); PIN(Wh[t]);
    }
    f32x4 Bb[8];
#pragma unroll
    for (int t = 0; t < 8; ++t) {
      Bb[t] = *(const f32x4*)(bias + t * 16 + 4 * g);
      PIN(Bb[t]);
    }

    float h0C[8];
#pragma unroll
    for (int r = 0; r < 4; ++r) {
      h0C[r]     = hsrc[(size_t)(b0 + c) * HH + 4 * g + r];
      h0C[4 + r] = hsrc[(size_t)(b0 + c) * HH + 16 + 4 * g + r];
    }
    bf16x8 h0B = mkB(hsrc + (size_t)(b0 + c) * HH + 8 * g);

    auto mkX = [&](f32x4 sa, f32x4 sb, float gsv) -> bf16x8 {
      uint32_t pkg = cvtpk(gsv, gsv);
      union { uint32_t u[4]; bf16x8 v; } t;
      uint32_t p0 = cvtpk(sa[0], sa[1]), p1 = cvtpk(sa[2], sa[3]);
      uint32_t p2 = cvtpk(sb[0], sb[1]), p3 = cvtpk(sb[2], sb[3]);
      t.u[0] = lo32 ? p0 : pkg;
      t.u[1] = lo32 ? p1 : pkg;
      t.u[2] = lo32 ? p2 : pkg;
      t.u[3] = lo32 ? p3 : pkg;
      return t.v;
    };

    const float* Sbase  = S  + (size_t)(b0 + c) * TT * DD + 8 * (g & 1);
    const float* gSbase = gS + (size_t)(b0 + c) * TT;

    // x prefetch, 2 steps deep
    f32x4 sa0 = *(const f32x4*)(Sbase + (size_t)(TT - 1) * DD);
    f32x4 sb0 = *(const f32x4*)(Sbase + (size_t)(TT - 1) * DD + 4);
    float gv0 = gSbase[TT - 1];
    f32x4 sa1 = *(const f32x4*)(Sbase + (size_t)(TT - 2) * DD);
    f32x4 sb1 = *(const f32x4*)(Sbase + (size_t)(TT - 2) * DD + 4);
    float gv1 = gSbase[TT - 2];

#pragma unroll 2
    for (int i = 0; i < TT; ++i) {
      int tn = TT - 3 - i; if (tn < 0) tn = 0;
      const float* p = Sbase + (size_t)tn * DD;
      f32x4 san = *(const f32x4*)p, sbn = *(const f32x4*)(p + 4);
      float gvn = gSbase[tn];

      bf16x8 xB = mkX(sa0, sb0, gv0);
      gruStep(Wi, Wh, Bb, xB, h0B, h0C);
      h0B = regroup(h0C);

      if (i >= 7) waitGE(1, i - 7);               // backpressure
      asm volatile("" ::: "memory");
      { U4 u; u.v = h0B; ring0[i & 7][lane] = u.q; }
      asm volatile("s_waitcnt lgkmcnt(0)" ::: "memory");
      if (lane == 0) flags[0] = i + 1;

      sa0 = sa1; sb0 = sb1; gv0 = gv1;
      sa1 = san; sb1 = sbn; gv1 = gvn;
    }
  } else {
    // ================= wave B: layer-1 + heads (consumer) ================
    bf16x8 Wi[6], Wh[6], We0, We1, Wo;
#pragma unroll
    for (int t = 0; t < 6; ++t) {
      Wi[t] = *(const bf16x8*)(W + ((12 + t) * 64 + lane) * 8);
      Wh[t] = *(const bf16x8*)(W + ((18 + t) * 64 + lane) * 8);
      PIN(Wi[t]); PIN(Wh[t]);
    }
    We0 = *(const bf16x8*)(W + (24 * 64 + lane) * 8);
    We1 = *(const bf16x8*)(W + (25 * 64 + lane) * 8);
    Wo  = *(const bf16x8*)(W + (26 * 64 + lane) * 8);
    PIN(We0); PIN(We1); PIN(Wo);
    f32x4 Bb[8];
#pragma unroll
    for (int t = 0; t < 8; ++t) {
      Bb[t] = *(const f32x4*)(bias + (8 + t) * 16 + 4 * g);
      PIN(Bb[t]);
    }
    f32x4 Be0 = *(const f32x4*)(bias + 16 * 16 + 4 * g);
    f32x4 Be1 = *(const f32x4*)(bias + 17 * 16 + 4 * g);
    f32x4 Bo  = *(const f32x4*)(bias + 18 * 16 + 4 * g);
    PIN(Be0); PIN(Be1); PIN(Bo);

    float h1C[8];
#pragma unroll
    for (int r = 0; r < 4; ++r) {
      h1C[r]     = hsrc[((size_t)BB + b0 + c) * HH + 4 * g + r];
      h1C[4 + r] = hsrc[((size_t)BB + b0 + c) * HH + 16 + 4 * g + r];
    }
    bf16x8 h1B = mkB(hsrc + ((size_t)BB + b0 + c) * HH + 8 * g);

    auto head = [&](bf16x8 h1f, int th) {
      f32x4 e0 = mfma_(We0, h1f, Be0);
      f32x4 e1 = mfma_(We1, h1f, Be1);
      float es[8];
#pragma unroll
      for (int r = 0; r < 4; ++r) {
        float a = e0[r], b = e1[r];
        es[r]     = a * sigm(a);
        es[4 + r] = b * sigm(b);
      }
      bf16x8 ef = regroup(es);
      f32x4 o = mfma_(Wo, ef, Bo);
      if (net == 0) {
        if (lane < 16) out[(size_t)(b0 + c) * TT + th] = o[0];
      } else {
        f32x4 so;
#pragma unroll
        for (int r = 0; r < 4; ++r) so[r] = sigm(o[r]);
        *(f32x4*)(out + (size_t)BB * TT +
                  ((size_t)(b0 + c) * TT + th) * DD + 4 * g) = so;
      }
    };

#pragma unroll 1
    for (int i = 0; i < TT; ++i) {
      waitGE(0, i + 1);                           // wait for h0(i)
      asm volatile("" ::: "memory");
      U4 u; u.q = ring0[i & 7][lane];
      asm volatile("s_waitcnt lgkmcnt(0)" ::: "memory");
      if (lane == 0) flags[1] = i + 1;            // slot free

      bf16x8 h1prev = h1B;                        // for head(i-1)
      gruStep(Wi, Wh, Bb, u.v, h1B, h1C);         // L1 step i
      if (i > 0) head(h1prev, TT - i);            // overlaps L1's latency
      h1B = regroup(h1C);
    }
    head(h1B, 0);
  }
}

// ---------------- launch ----------------
extern "C" void kernel_launch(void* const* d_in, const int* in_sizes, int n_in,
                              void* d_out, int out_size, void* d_ws,
                              size_t ws_size, hipStream_t stream) {
  const float* S   = (const float*)d_in[0];
  const float* gS  = (const float*)d_in[1];
  const float* hp0 = (const float*)d_in[5];
  const float* hd0 = (const float*)d_in[6];
  uint8_t* ws = (uint8_t*)d_ws;

  prep_net<<<1, 256, 0, stream>>>(
      (const float*)d_in[7],  (const float*)d_in[8],  (const float*)d_in[9],
      (const float*)d_in[10], (const float*)d_in[11], (const float*)d_in[12],
      (const float*)d_in[13], (const float*)d_in[14], (const float*)d_in[15],
      (const float*)d_in[16], (const float*)d_in[17], (const float*)d_in[18],
      (const float*)d_in[19], (const float*)d_in[20], (const float*)d_in[21],
      (const float*)d_in[22], 1, ws);
  prep_net<<<1, 256, 0, stream>>>(
      (const float*)d_in[23], (const float*)d_in[24], (const float*)d_in[25],
      (const float*)d_in[26], (const float*)d_in[27], (const float*)d_in[28],
      (const float*)d_in[29], (const float*)d_in[30], (const float*)d_in[31],
      (const float*)d_in[32], (const float*)d_in[33], (const float*)d_in[34],
      (const float*)d_in[35], (const float*)d_in[36], (const float*)d_in[37],
      (const float*)d_in[38], 16, ws + 32768);

  rnn_fused<<<dim3((BB / 16) * 2), dim3(128), 0, stream>>>(S, gS, hp0, hd0,
                                                           ws, (float*)d_out);
}

// Round 9
// 151.374 us; speedup vs baseline: 1.0802x; 1.0802x over previous
//
#include <hip/hip_runtime.h>
#include <hip/hip_bf16.h>
#include <stdint.h>

#define DI __device__ __forceinline__

typedef float f32x4 __attribute__((ext_vector_type(4)));
typedef short bf16x8 __attribute__((ext_vector_type(8)));

constexpr int BB = 8192, TT = 128, DD = 16, HH = 32;
constexpr float kEPS = 1e-5f;
constexpr float kLOG2E = 1.44269504088896340736f;

// ---------------- helpers ----------------
DI float rcpf_(float x) { return __builtin_amdgcn_rcpf(x); }
DI float exp2f_(float x) { return __builtin_amdgcn_exp2f(x); }
DI float sigm(float x) { return rcpf_(1.0f + exp2f_(-kLOG2E * x)); }

DI uint32_t cvtpk(float lo, float hi) {
  uint32_t r;
  asm("v_cvt_pk_bf16_f32 %0, %1, %2" : "=v"(r) : "v"(lo), "v"(hi));
  return r;
}

DI f32x4 mfma_(bf16x8 a, bf16x8 b, f32x4 c) {
  return __builtin_amdgcn_mfma_f32_16x16x32_bf16(a, b, c, 0, 0, 0);
}

union U4 { uint4 q; bf16x8 v; uint32_t u[4]; };

// ---------------- weight prep (per net) ----------------
// W tiles are the MFMA *A* operand, state is *B*.
// k-slot permutation pi (both operands):  pi(8g+j) = j<4 ? 4g+j : 16+4g+(j-4)
// With pi, the MFMA C-layout (lane c+16g holds dims {4g+r, 16+4g+r}) IS the
// B-frag layout -> recurrent state repack = 4 in-lane cvt_pk, NO cross-lane.
// ws per-net block (32 KiB stride):
//   u16[27*512]: 27 tiles (Wih0 r0 r1 z0 z1 n0 n1 | Whh0 ... | Wih1 ... |
//                Whh1 ... | emb e0 e1 | out), each tile = 64 lanes x 8 bf16.
//   f32[304] at byte 27648: 19 bias tiles x 16
//   (L0: r0 r1 z0 z1 i0 i1 h0 h1 | L1: same | e0 e1 | out)
__global__ void prep_net(const float* Wih0, const float* Whh0,
                         const float* bih0, const float* bhh0,
                         const float* Wih1, const float* Whh1,
                         const float* bih1, const float* bhh1,
                         const float* embW, const float* embB,
                         const float* bng, const float* bnb,
                         const float* bnm, const float* bnv,
                         const float* outW, const float* outB,
                         int outDim, uint8_t* wsbase) {
  int tid = threadIdx.x;
  uint16_t* W = (uint16_t*)wsbase;
  float* bias = (float*)(wsbase + 27648);
  auto cvt = [](float f) -> uint16_t {
    union { float f; uint32_t u; } v; v.f = f;
    uint32_t u = v.u;
    return (uint16_t)((u + 0x7FFF + ((u >> 16) & 1)) >> 16);  // RNE
  };
  for (int idx = tid; idx < 27 * 64; idx += 256) {
    int tile = idx >> 6, l = idx & 63, cc = l & 15, gg = l >> 4;
    uint16_t* dst = W + (size_t)idx * 8;
    if (tile < 24) {
      const float* mats[4] = {Wih0, Whh0, Wih1, Whh1};
      const float* src = mats[tile / 6];
      int sub = tile % 6;                   // r0 r1 z0 z1 n0 n1
      int row = sub * 16 + cc;              // rows: r 0-31, z 32-63, n 64-95
      float sc = (sub < 4) ? -kLOG2E : 2.0f * kLOG2E;
#pragma unroll
      for (int j = 0; j < 8; ++j) {
        int k = (j < 4) ? 4 * gg + j : 16 + 4 * gg + (j - 4);  // pi
        dst[j] = cvt(src[row * 32 + k] * sc);
      }
    } else if (tile < 26) {
      int row = (tile - 24) * 16 + cc;
      float a = bng[row] * rsqrtf(bnv[row] + kEPS);
#pragma unroll
      for (int j = 0; j < 8; ++j) {
        int k = (j < 4) ? 4 * gg + j : 16 + 4 * gg + (j - 4);  // pi
        dst[j] = cvt(embW[row * 32 + k] * a);
      }
    } else {
      int rrow = (cc < outDim) ? cc : 0;
      float sc = (cc < outDim) ? 1.0f : 0.0f;
#pragma unroll
      for (int j = 0; j < 8; ++j) {
        int k = (j < 4) ? 4 * gg + j : 16 + 4 * gg + (j - 4);  // pi
        dst[j] = cvt(outW[rrow * 32 + k] * sc);
      }
    }
  }
  for (int idx = tid; idx < 304; idx += 256) {
    int tile = idx >> 4, n = idx & 15;
    float v;
    if (tile < 8) {
      if (tile < 4)      v = (bih0[tile * 16 + n] + bhh0[tile * 16 + n]) * (-kLOG2E);
      else if (tile < 6) v = bih0[64 + (tile - 4) * 16 + n] * (2.0f * kLOG2E);
      else               v = bhh0[64 + (tile - 6) * 16 + n] * (2.0f * kLOG2E);
    } else if (tile < 16) {
      int tt = tile - 8;
      if (tt < 4)        v = (bih1[tt * 16 + n] + bhh1[tt * 16 + n]) * (-kLOG2E);
      else if (tt < 6)   v = bih1[64 + (tt - 4) * 16 + n] * (2.0f * kLOG2E);
      else               v = bhh1[64 + (tt - 6) * 16 + n] * (2.0f * kLOG2E);
    } else if (tile < 18) {
      int nn = (tile - 16) * 16 + n;
      float a = bng[nn] * rsqrtf(bnv[nn] + kEPS);
      v = a * (embB[nn] - bnm[nn]) + bnb[nn];
    } else {
      v = (n < outDim) ? outB[n] : 0.0f;
    }
    bias[idx] = v;
  }
}

// ------- fused RNN + heads: async 2-wave split, ZERO-permute recurrence ----
// Block = 128 threads = 2 waves, one batch group (16 rows) of one net.
// Wave A: layer-0 recurrence -> h0 ring (depth 8); wave B: layer-1 + head.
// Flag sync batched every 4 steps. No ds_bpermute anywhere.
__global__ __launch_bounds__(128, 2) void rnn_fused(
    const float* __restrict__ S, const float* __restrict__ gS,
    const float* __restrict__ hp0, const float* __restrict__ hd0,
    const uint8_t* __restrict__ ws, float* __restrict__ out) {
  const int tid = threadIdx.x, lane = tid & 63, wid = tid >> 6;
  const int net = blockIdx.x & 1;                 // 0 = price, 1 = delta
  const int b0 = (blockIdx.x >> 1) * 16;
  const int c = lane & 15, g = lane >> 4;

  const uint16_t* W = (const uint16_t*)(ws + net * 32768);
  const float* bias = (const float*)(ws + net * 32768 + 27648);
  const float* hsrc = net ? hd0 : hp0;

  __shared__ uint4 ring0[8][64];                  // h0 B-frags, depth 8
  __shared__ volatile int flags[2];               // 0 = prod, 1 = cons
  if (tid < 2) flags[tid] = 0;
  __syncthreads();                                // the only block barrier

  auto waitGE = [&](int idx, int target) {
    if (flags[idx] >= target) return;
    do { __builtin_amdgcn_s_sleep(1); } while (flags[idx] < target);
  };

  // acc/C-layout h[8] -> B-frag: pure in-lane pack (pi layout)
  auto packB = [&](const float (&v)[8]) -> bf16x8 {
    U4 t;
    t.u[0] = cvtpk(v[0], v[1]); t.u[1] = cvtpk(v[2], v[3]);
    t.u[2] = cvtpk(v[4], v[5]); t.u[3] = cvtpk(v[6], v[7]);
    return t.v;
  };

  // GRU step, fused-rcp algebra: h' = [(h-Ez)+En*(h+Ez)]*rcp[(1+En)(1+Ez)]
  auto gruStep = [&](const bf16x8 (&Wi)[6], const bf16x8 (&Wh)[6],
                     const f32x4 (&Bb)[8], bf16x8 xf, bf16x8 hf,
                     float (&hC)[8]) {
    f32x4 r0 = mfma_(Wi[0], xf, Bb[0]); r0 = mfma_(Wh[0], hf, r0);
    f32x4 r1 = mfma_(Wi[1], xf, Bb[1]); r1 = mfma_(Wh[1], hf, r1);
    f32x4 z0 = mfma_(Wi[2], xf, Bb[2]); z0 = mfma_(Wh[2], hf, z0);
    f32x4 z1 = mfma_(Wi[3], xf, Bb[3]); z1 = mfma_(Wh[3], hf, z1);
    f32x4 ni0 = mfma_(Wi[4], xf, Bb[4]);
    f32x4 ni1 = mfma_(Wi[5], xf, Bb[5]);
    f32x4 nh0 = mfma_(Wh[4], hf, Bb[6]);
    f32x4 nh1 = mfma_(Wh[5], hf, Bb[7]);
#pragma unroll
    for (int r = 0; r < 4; ++r) {
      float rg0 = rcpf_(1.0f + exp2f_(r0[r]));
      float rg1 = rcpf_(1.0f + exp2f_(r1[r]));
      float w0 = ni0[r] + rg0 * nh0[r];
      float w1 = ni1[r] + rg1 * nh1[r];
      float En0 = exp2f_(w0), En1 = exp2f_(w1);
      float Ez0 = exp2f_(z0[r]), Ez1 = exp2f_(z1[r]);
      float hv0 = hC[r], hv1 = hC[4 + r];
      float num0 = (hv0 - Ez0) + En0 * (hv0 + Ez0);
      float num1 = (hv1 - Ez1) + En1 * (hv1 + Ez1);
      float den0 = (1.0f + En0) * (1.0f + Ez0);
      float den1 = (1.0f + En1) * (1.0f + Ez1);
      hC[r]     = num0 * rcpf_(den0);
      hC[4 + r] = num1 * rcpf_(den1);
    }
  };

  // initial state load in pi B-frag layout + acc layout (same dims per lane)
  auto loadState = [&](const float* row, float (&hC)[8]) -> bf16x8 {
    f32x4 a = *(const f32x4*)(row + 4 * g);        // dims 4g..4g+3
    f32x4 b = *(const f32x4*)(row + 16 + 4 * g);   // dims 16+4g..16+4g+3
#pragma unroll
    for (int r = 0; r < 4; ++r) { hC[r] = a[r]; hC[4 + r] = b[r]; }
    U4 t;
    t.u[0] = cvtpk(a[0], a[1]); t.u[1] = cvtpk(a[2], a[3]);
    t.u[2] = cvtpk(b[0], b[1]); t.u[3] = cvtpk(b[2], b[3]);
    return t.v;
  };

  if (wid == 0) {
    // ================= wave A: layer-0 recurrence (producer) =============
    bf16x8 Wi[6], Wh[6];
#pragma unroll
    for (int t = 0; t < 6; ++t) {
      Wi[t] = *(const bf16x8*)(W + ((0 + t) * 64 + lane) * 8);
      Wh[t] = *(const bf16x8*)(W + ((6 + t) * 64 + lane) * 8);
    }
    f32x4 Bb[8];
#pragma unroll
    for (int t = 0; t < 8; ++t)
      Bb[t] = *(const f32x4*)(bias + t * 16 + 4 * g);

    float h0C[8];
    bf16x8 h0B = loadState(hsrc + (size_t)(b0 + c) * HH, h0C);

    // x B-frag (pi layout): slots j<4 = S[4g+j], j>=4 = gS broadcast.
    auto mkX = [&](f32x4 sv, float gsv) -> bf16x8 {
      uint32_t pkg = cvtpk(gsv, gsv);
      U4 t;
      t.u[0] = cvtpk(sv[0], sv[1]);
      t.u[1] = cvtpk(sv[2], sv[3]);
      t.u[2] = pkg;
      t.u[3] = pkg;
      return t.v;
    };

    const float* Sbase  = S  + (size_t)(b0 + c) * TT * DD + 4 * g;
    const float* gSbase = gS + (size_t)(b0 + c) * TT;

    // x prefetch, 2 steps deep (each lane: one f32x4 + one scalar)
    f32x4 sv0 = *(const f32x4*)(Sbase + (size_t)(TT - 1) * DD);
    float gv0 = gSbase[TT - 1];
    f32x4 sv1 = *(const f32x4*)(Sbase + (size_t)(TT - 2) * DD);
    float gv1 = gSbase[TT - 2];

#pragma unroll 2
    for (int i = 0; i < TT; ++i) {
      int tn = TT - 3 - i; if (tn < 0) tn = 0;
      f32x4 svn = *(const f32x4*)(Sbase + (size_t)tn * DD);
      float gvn = gSbase[tn];

      bf16x8 xB = mkX(sv0, gv0);
      gruStep(Wi, Wh, Bb, xB, h0B, h0C);
      h0B = packB(h0C);

      if (i >= 8 && (i & 3) == 0) waitGE(1, i - 4);   // batched backpressure
      asm volatile("" ::: "memory");
      { U4 u; u.v = h0B; ring0[i & 7][lane] = u.q; }
      if ((i & 3) == 3) {
        asm volatile("s_waitcnt lgkmcnt(0)" ::: "memory");
        if (lane == 0) flags[0] = i + 1;
      }

      sv0 = sv1; gv0 = gv1;
      sv1 = svn; gv1 = gvn;
    }
  } else {
    // ================= wave B: layer-1 + heads (consumer) ================
    bf16x8 Wi[6], Wh[6], We0, We1, Wo;
#pragma unroll
    for (int t = 0; t < 6; ++t) {
      Wi[t] = *(const bf16x8*)(W + ((12 + t) * 64 + lane) * 8);
      Wh[t] = *(const bf16x8*)(W + ((18 + t) * 64 + lane) * 8);
    }
    We0 = *(const bf16x8*)(W + (24 * 64 + lane) * 8);
    We1 = *(const bf16x8*)(W + (25 * 64 + lane) * 8);
    Wo  = *(const bf16x8*)(W + (26 * 64 + lane) * 8);
    f32x4 Bb[8];
#pragma unroll
    for (int t = 0; t < 8; ++t)
      Bb[t] = *(const f32x4*)(bias + (8 + t) * 16 + 4 * g);
    const f32x4 Be0 = *(const f32x4*)(bias + 16 * 16 + 4 * g);
    const f32x4 Be1 = *(const f32x4*)(bias + 17 * 16 + 4 * g);
    const f32x4 Bo  = *(const f32x4*)(bias + 18 * 16 + 4 * g);

    float h1C[8];
    bf16x8 h1B = loadState(hsrc + ((size_t)BB + b0 + c) * HH, h1C);

    auto head = [&](bf16x8 h1f, int th) {
      f32x4 e0 = mfma_(We0, h1f, Be0);
      f32x4 e1 = mfma_(We1, h1f, Be1);
      float es[8];
#pragma unroll
      for (int r = 0; r < 4; ++r) {
        float a = e0[r], b = e1[r];
        es[r]     = a * sigm(a);
        es[4 + r] = b * sigm(b);
      }
      bf16x8 ef = packB(es);                      // in-lane, pi layout
      f32x4 o = mfma_(Wo, ef, Bo);
      if (net == 0) {
        if (lane < 16) out[(size_t)(b0 + c) * TT + th] = o[0];
      } else {
        f32x4 so;
#pragma unroll
        for (int r = 0; r < 4; ++r) so[r] = sigm(o[r]);
        *(f32x4*)(out + (size_t)BB * TT +
                  ((size_t)(b0 + c) * TT + th) * DD + 4 * g) = so;
      }
    };

#pragma unroll 1
    for (int i = 0; i < TT; ++i) {
      if ((i & 3) == 0) waitGE(0, i + 4);         // batched wait (A 4 ahead)
      asm volatile("" ::: "memory");
      U4 u; u.q = ring0[i & 7][lane];
      asm volatile("s_waitcnt lgkmcnt(0)" ::: "memory");
      if ((i & 3) == 3 && lane == 0) flags[1] = i + 1;   // slots free

      bf16x8 h1prev = h1B;                        // for head(i-1)
      gruStep(Wi, Wh, Bb, u.v, h1B, h1C);         // L1 step i
      if (i > 0) head(h1prev, TT - i);            // overlaps L1's latency
      h1B = packB(h1C);
    }
    head(h1B, 0);
  }
}

// ---------------- launch ----------------
extern "C" void kernel_launch(void* const* d_in, const int* in_sizes, int n_in,
                              void* d_out, int out_size, void* d_ws,
                              size_t ws_size, hipStream_t stream) {
  const float* S   = (const float*)d_in[0];
  const float* gS  = (const float*)d_in[1];
  const float* hp0 = (const float*)d_in[5];
  const float* hd0 = (const float*)d_in[6];
  uint8_t* ws = (uint8_t*)d_ws;

  prep_net<<<1, 256, 0, stream>>>(
      (const float*)d_in[7],  (const float*)d_in[8],  (const float*)d_in[9],
      (const float*)d_in[10], (const float*)d_in[11], (const float*)d_in[12],
      (const float*)d_in[13], (const float*)d_in[14], (const float*)d_in[15],
      (const float*)d_in[16], (const float*)d_in[17], (const float*)d_in[18],
      (const float*)d_in[19], (const float*)d_in[20], (const float*)d_in[21],
      (const float*)d_in[22], 1, ws);
  prep_net<<<1, 256, 0, stream>>>(
      (const float*)d_in[23], (const float*)d_in[24], (const float*)d_in[25],
      (const float*)d_in[26], (const float*)d_in[27], (const float*)d_in[28],
      (const float*)d_in[29], (const float*)d_in[30], (const float*)d_in[31],
      (const float*)d_in[32], (const float*)d_in[33], (const float*)d_in[34],
      (const float*)d_in[35], (const float*)d_in[36], (const float*)d_in[37],
      (const float*)d_in[38], 16, ws + 32768);

  rnn_fused<<<dim3((BB / 16) * 2), dim3(128), 0, stream>>>(S, gS, hp0, hd0,
                                                           ws, (float*)d_out);
}